// Round 20
// baseline (733.069 us; speedup 1.0000x reference)
//
#include <hip/hip_runtime.h>
#include <hip/hip_bf16.h>
#include <type_traits>

// ---- problem constants (fixed by the reference) ----
#define N_BONDS 196608
#define HID     256
#define NSEG    4096
#define SMSCALE 0.17677669529663687f  // D^-0.5, D=32
#define LN_EPS  1e-5f
#define CHUNK   8                     // bonds per block in segment kernels

typedef __hip_bfloat16 bf16;
typedef __attribute__((ext_vector_type(8))) short short8_t;  // 8 x bf16 (4 VGPR)
typedef __attribute__((ext_vector_type(4))) float f32x4_t;

__device__ __forceinline__ float bf2f(bf16 x) { return __bfloat162float(x); }
__device__ __forceinline__ short f2bs(float f) {
    union { bf16 b; short s; } cv; cv.b = __float2bfloat16(f); return cv.s;
}
__device__ __forceinline__ float us2f(ushort u) {
    union { ushort u; bf16 b; } cv; cv.u = u; return __bfloat162float(cv.b);
}

// 32-lane-group sum inside a 64-lane wave (xor masks < 32 stay inside the head group)
__device__ __forceinline__ float gsum32(float x) {
#pragma unroll
    for (int m = 16; m >= 1; m >>= 1) x += __shfl_xor(x, m);
    return x;
}

// ---------------- f32 -> bf16 cast (x4 vectorized) ----------------
__global__ void cast_kernel(const float* __restrict__ src, ushort* __restrict__ dst, int n4) {
    int i = blockIdx.x * blockDim.x + threadIdx.x;
    const int stride = gridDim.x * blockDim.x;
    for (; i < n4; i += stride) {
        float4 v = reinterpret_cast<const float4*>(src)[i];
        union { ushort4 u; bf16 b[4]; } cv;
        cv.b[0] = __float2bfloat16(v.x);
        cv.b[1] = __float2bfloat16(v.y);
        cv.b[2] = __float2bfloat16(v.z);
        cv.b[3] = __float2bfloat16(v.w);
        reinterpret_cast<ushort4*>(dst)[i] = cv.u;
    }
}

// ---------------- GEMM: C[n,j] = sum_i A[n,i] * W[j,i]  (torch Linear, B^T form) ----------------
// VERBATIM from R13 (known-pass). W f32 -> bf16 during LDS staging; A bf16. Used for W_o.
template <typename AT, typename OutT>
__global__ __launch_bounds__(256, 2) void gemm_bt(const AT* __restrict__ A,
                                                  const float* __restrict__ W,
                                                  OutT* __restrict__ C) {
    __shared__ __align__(16) char lds[128 * 512];
    const int t = threadIdx.x;
    const int colhalf = blockIdx.y;
#pragma unroll
    for (int it = 0; it < 16; ++it) {
        int c = it * 256 + t;
        int j = c >> 5, kc = c & 31;
        const float* wp = W + ((colhalf << 7) + j) * HID + (kc << 3);
        float4 w0 = *reinterpret_cast<const float4*>(wp);
        float4 w1 = *reinterpret_cast<const float4*>(wp + 4);
        union { uint4 u; short s[8]; } cv;
        cv.s[0] = f2bs(w0.x); cv.s[1] = f2bs(w0.y); cv.s[2] = f2bs(w0.z); cv.s[3] = f2bs(w0.w);
        cv.s[4] = f2bs(w1.x); cv.s[5] = f2bs(w1.y); cv.s[6] = f2bs(w1.z); cv.s[7] = f2bs(w1.w);
        *reinterpret_cast<uint4*>(lds + j * 512 + ((kc << 4) ^ ((j & 7) << 4))) = cv.u;
    }
    __syncthreads();

    const int wave = t >> 6, lane = t & 63;
    const int lr = lane & 15, lk = lane >> 4;
    const long rowbase = (long)blockIdx.x * 128 + wave * 32;

    f32x4_t acc[2][8];
#pragma unroll
    for (int r = 0; r < 2; ++r)
#pragma unroll
        for (int cc = 0; cc < 8; ++cc) acc[r][cc] = (f32x4_t){0.f, 0.f, 0.f, 0.f};

    const AT* a0 = A + (rowbase + lr) * HID;
    const AT* a1 = a0 + 16 * HID;
#pragma unroll
    for (int k0 = 0; k0 < HID; k0 += 32) {
        const int koff = k0 + lk * 8;
        short8_t af0, af1;
        if constexpr (std::is_same_v<AT, float>) {
            float4 x0 = *reinterpret_cast<const float4*>(a0 + koff);
            float4 x1 = *reinterpret_cast<const float4*>(a0 + koff + 4);
            float4 y0 = *reinterpret_cast<const float4*>(a1 + koff);
            float4 y1 = *reinterpret_cast<const float4*>(a1 + koff + 4);
            af0[0] = f2bs(x0.x); af0[1] = f2bs(x0.y); af0[2] = f2bs(x0.z); af0[3] = f2bs(x0.w);
            af0[4] = f2bs(x1.x); af0[5] = f2bs(x1.y); af0[6] = f2bs(x1.z); af0[7] = f2bs(x1.w);
            af1[0] = f2bs(y0.x); af1[1] = f2bs(y0.y); af1[2] = f2bs(y0.z); af1[3] = f2bs(y0.w);
            af1[4] = f2bs(y1.x); af1[5] = f2bs(y1.y); af1[6] = f2bs(y1.z); af1[7] = f2bs(y1.w);
        } else {
            af0 = *reinterpret_cast<const short8_t*>(a0 + koff);
            af1 = *reinterpret_cast<const short8_t*>(a1 + koff);
        }
#pragma unroll
        for (int cc = 0; cc < 8; ++cc) {
            const int j = cc * 16 + lr;
            short8_t bfr = *reinterpret_cast<const short8_t*>(
                lds + j * 512 + (((k0 << 1) + (lk << 4)) ^ ((j & 7) << 4)));
            acc[0][cc] = __builtin_amdgcn_mfma_f32_16x16x32_bf16(af0, bfr, acc[0][cc], 0, 0, 0);
            acc[1][cc] = __builtin_amdgcn_mfma_f32_16x16x32_bf16(af1, bfr, acc[1][cc], 0, 0, 0);
        }
    }
    // C/D layout (verified m89): col = lane&15, row = (lane>>4)*4 + reg
#pragma unroll
    for (int r = 0; r < 2; ++r) {
#pragma unroll
        for (int cc = 0; cc < 8; ++cc) {
            const int col = (colhalf << 7) + cc * 16 + lr;
#pragma unroll
            for (int reg = 0; reg < 4; ++reg) {
                const long row = rowbase + r * 16 + lk * 4 + reg;
                const float v = acc[r][cc][reg];
                if constexpr (sizeof(OutT) == 2) C[row * HID + col] = __float2bfloat16(v);
                else                             C[row * HID + col] = v;
            }
        }
    }
}

// ---------------- merged QKV with A-tile in LDS: one block per 128 rows, 6 phases ------------
// R17-R19 lesson: staging W makes every (matrix, half) pass re-stream 100MB of A (R17 FETCH
// 300MB @184us; quarter tiles worse). Invert: stage the A-tile (128x256 bf16 = 64KB, plain
// uint4 copy) ONCE, compute all 3 matrices x 2 halves from it. A is read from HBM exactly
// once (100MB total); W fragments come from pre-cast bf16 buffers (128KB each, L2-hot,
// shared by all blocks). LDS read pattern (row x*16+lr, col k0+lk*8, same XOR swizzle) is
// byte-identical to the proven W-path; MFMA operand roles and C-write mapping unchanged.
__global__ __launch_bounds__(256, 2) void qkv_gemm(const ushort* __restrict__ A,
                                                   const ushort* __restrict__ Wqb,
                                                   const ushort* __restrict__ Wkb,
                                                   const ushort* __restrict__ Wvb,
                                                   bf16* __restrict__ Q,
                                                   bf16* __restrict__ K,
                                                   bf16* __restrict__ V) {
    __shared__ __align__(16) char lds[128 * 512];
    const int t = threadIdx.x;
    const long row0 = (long)blockIdx.x * 128;

    // stage A tile: 128 rows x 32 chunks of 8 bf16 (no cast -- already bf16)
#pragma unroll
    for (int it = 0; it < 16; ++it) {
        int c = it * 256 + t;
        int j = c >> 5, kc = c & 31;
        uint4 val = *reinterpret_cast<const uint4*>(A + (row0 + j) * HID + (kc << 3));
        *reinterpret_cast<uint4*>(lds + j * 512 + ((kc << 4) ^ ((j & 7) << 4))) = val;
    }
    __syncthreads();

    const int wave = t >> 6, lane = t & 63;
    const int lr = lane & 15, lk = lane >> 4;
    const int r0 = wave * 32 + lr;        // local A row for af0 ((r0&7) == (lr&7))
    const int r1 = r0 + 16;               // local A row for af1

#pragma unroll
    for (int m = 0; m < 3; ++m) {
        const ushort* W = (m == 0) ? Wqb : (m == 1) ? Wkb : Wvb;
        bf16* C = (m == 0) ? Q : (m == 1) ? K : V;
#pragma unroll
        for (int ch = 0; ch < 2; ++ch) {
            f32x4_t acc[2][8];
#pragma unroll
            for (int r = 0; r < 2; ++r)
#pragma unroll
                for (int cc = 0; cc < 8; ++cc) acc[r][cc] = (f32x4_t){0.f, 0.f, 0.f, 0.f};

#pragma unroll
            for (int k0 = 0; k0 < HID; k0 += 32) {
                short8_t af0 = *reinterpret_cast<const short8_t*>(
                    lds + r0 * 512 + (((k0 << 1) + (lk << 4)) ^ ((lr & 7) << 4)));
                short8_t af1 = *reinterpret_cast<const short8_t*>(
                    lds + r1 * 512 + (((k0 << 1) + (lk << 4)) ^ ((lr & 7) << 4)));
#pragma unroll
                for (int cc = 0; cc < 8; ++cc) {
                    const int j = (ch << 7) + cc * 16 + lr;
                    short8_t bfr = *reinterpret_cast<const short8_t*>(W + j * HID + k0 + lk * 8);
                    acc[0][cc] = __builtin_amdgcn_mfma_f32_16x16x32_bf16(af0, bfr, acc[0][cc], 0, 0, 0);
                    acc[1][cc] = __builtin_amdgcn_mfma_f32_16x16x32_bf16(af1, bfr, acc[1][cc], 0, 0, 0);
                }
            }
#pragma unroll
            for (int r = 0; r < 2; ++r) {
#pragma unroll
                for (int cc = 0; cc < 8; ++cc) {
                    const int col = (ch << 7) + cc * 16 + lr;
#pragma unroll
                    for (int reg = 0; reg < 4; ++reg) {
                        const long row = row0 + wave * 32 + r * 16 + lk * 4 + reg;
                        C[row * HID + col] = __float2bfloat16(acc[r][cc][reg]);
                    }
                }
            }
        }
    }
}

// ---------------- alpha = softmax_d(q*w_alpha*scale); gq = segment_sum(alpha*q) ----------------
// VERBATIM from R10 (known-pass).
__global__ __launch_bounds__(256) void alpha_gq_kernel(const bf16* __restrict__ qb,
                                                       const float* __restrict__ w_alpha,
                                                       const int* __restrict__ seg,
                                                       float* __restrict__ gq) {
    const int j = threadIdx.x;
    const float wa = w_alpha[j & 31] * SMSCALE;
    const long n0 = (long)blockIdx.x * CHUNK;
    float acc = 0.f;
    int cur = -1;
    for (int i = 0; i < CHUNK; ++i) {
        const long n = n0 + i;
        const int s = seg[n];
        const float qv = bf2f(qb[n * HID + j]);
        const float e = __expf(qv * wa);
        const float ssum = gsum32(e);
        const float alpha = e / ssum;
        if (s != cur) {
            if (cur >= 0) atomicAdd(&gq[(long)cur * HID + j], acc);
            acc = 0.f;
            cur = s;
        }
        acc += alpha * qv;
    }
    atomicAdd(&gq[(long)cur * HID + j], acc);
}

// ---------------- p = gq[seg]*k; beta = softmax_d(p*w_beta*scale); gk = segment_sum(beta*p) ----
// VERBATIM from R10 (known-pass).
__global__ __launch_bounds__(256) void beta_gk_kernel(const bf16* __restrict__ kb,
                                                      const float* __restrict__ gq,
                                                      const float* __restrict__ w_beta,
                                                      const int* __restrict__ seg,
                                                      float* __restrict__ gk) {
    const int j = threadIdx.x;
    const float wb = w_beta[j & 31] * SMSCALE;
    const long n0 = (long)blockIdx.x * CHUNK;
    float acc = 0.f;
    int cur = -1;
    for (int i = 0; i < CHUNK; ++i) {
        const long n = n0 + i;
        const int s = seg[n];
        const float kv = bf2f(kb[n * HID + j]);
        const float p = gq[(long)s * HID + j] * kv;
        const float e = __expf(p * wb);
        const float ssum = gsum32(e);
        const float beta = e / ssum;
        if (s != cur) {
            if (cur >= 0) atomicAdd(&gk[(long)cur * HID + j], acc);
            acc = 0.f;
            cur = s;
        }
        acc += beta * p;
    }
    atomicAdd(&gk[(long)cur * HID + j], acc);
}

// ---------------- act = relu((gk[seg]*v) @ W_r^T per head + q) via bf16 hi/lo MFMA -----------
// VERBATIM from R12/R13 (known-pass).
__global__ __launch_bounds__(256) void act_mfma_kernel(const ushort* __restrict__ vb,
                                                       const ushort* __restrict__ qb,
                                                       const float* __restrict__ gk,
                                                       const float* __restrict__ Wr,
                                                       const int* __restrict__ seg,
                                                       ushort* __restrict__ act) {
    const int t = threadIdx.x;
    const int wave = t >> 6, lane = t & 63;
    const int lr = lane & 15, lk = lane >> 4;

    short8_t bhi[2], blo[2];
#pragma unroll
    for (int ct = 0; ct < 2; ++ct) {
        const float* wr = Wr + (ct * 16 + lr) * 32 + lk * 8;
#pragma unroll
        for (int e = 0; e < 8; ++e) {
            const float w = wr[e];
            const short h = f2bs(w);
            bhi[ct][e] = h;
            blo[ct][e] = f2bs(w - us2f((ushort)h));
        }
    }

    const long rowblock = (long)blockIdx.x * 256 + wave * 64;
#pragma unroll
    for (int rt = 0; rt < 4; ++rt) {
        const long rtbase = rowblock + rt * 16;
        const long arow = rtbase + lr;
        const int n = (int)(arow >> 3), h = (int)(arow & 7);
        const int sid = seg[n];
        short8_t v8 = *reinterpret_cast<const short8_t*>(vb + arow * 32 + lk * 8);
        const float* gp = gk + (long)sid * HID + h * 32 + lk * 8;
        float4 g0 = *reinterpret_cast<const float4*>(gp);
        float4 g1 = *reinterpret_cast<const float4*>(gp + 4);
        float kvi[8];
        kvi[0] = g0.x * us2f((ushort)v8[0]);
        kvi[1] = g0.y * us2f((ushort)v8[1]);
        kvi[2] = g0.z * us2f((ushort)v8[2]);
        kvi[3] = g0.w * us2f((ushort)v8[3]);
        kvi[4] = g1.x * us2f((ushort)v8[4]);
        kvi[5] = g1.y * us2f((ushort)v8[5]);
        kvi[6] = g1.z * us2f((ushort)v8[6]);
        kvi[7] = g1.w * us2f((ushort)v8[7]);
        short8_t ahi, alo;
#pragma unroll
        for (int e = 0; e < 8; ++e) {
            const short hh = f2bs(kvi[e]);
            ahi[e] = hh;
            alo[e] = f2bs(kvi[e] - us2f((ushort)hh));
        }
#pragma unroll
        for (int ct = 0; ct < 2; ++ct) {
            f32x4_t c = (f32x4_t){0.f, 0.f, 0.f, 0.f};
            c = __builtin_amdgcn_mfma_f32_16x16x32_bf16(ahi, bhi[ct], c, 0, 0, 0);
            c = __builtin_amdgcn_mfma_f32_16x16x32_bf16(alo, bhi[ct], c, 0, 0, 0);
            c = __builtin_amdgcn_mfma_f32_16x16x32_bf16(ahi, blo[ct], c, 0, 0, 0);
#pragma unroll
            for (int reg = 0; reg < 4; ++reg) {
                const long row = rtbase + lk * 4 + reg;
                const long idx = row * 32 + ct * 16 + lr;
                act[idx] = (ushort)f2bs(fmaxf(c[reg] + us2f(qb[idx]), 0.f));
            }
        }
    }
}

// ---------------- LayerNorm: one wave per row, bf16 tmp input, write d_out row n+1 ----------
// VERBATIM from R11/R13 (known-pass).
__global__ __launch_bounds__(256) void ln_kernel(const ushort* __restrict__ tmp,
                                                 const float* __restrict__ b_o,
                                                 const float* __restrict__ gamma,
                                                 const float* __restrict__ beta_ln,
                                                 float* __restrict__ out) {
    const int wave = threadIdx.x >> 6, lane = threadIdx.x & 63;
    const long row = (long)blockIdx.x * 4 + wave;
    const float4 bo = reinterpret_cast<const float4*>(b_o)[lane];
    const float4 g = reinterpret_cast<const float4*>(gamma)[lane];
    const float4 bl = reinterpret_cast<const float4*>(beta_ln)[lane];
    const ushort4 xr = reinterpret_cast<const ushort4*>(tmp + row * HID)[lane];
    float4 x = {us2f(xr.x) + bo.x, us2f(xr.y) + bo.y, us2f(xr.z) + bo.z, us2f(xr.w) + bo.w};
    float s = x.x + x.y + x.z + x.w;
#pragma unroll
    for (int m = 32; m >= 1; m >>= 1) s += __shfl_xor(s, m);
    const float mu = s * (1.f / HID);
    float4 dx = {x.x - mu, x.y - mu, x.z - mu, x.w - mu};
    float sq = dx.x * dx.x + dx.y * dx.y + dx.z * dx.z + dx.w * dx.w;
#pragma unroll
    for (int m = 32; m >= 1; m >>= 1) sq += __shfl_xor(sq, m);
    const float r = rsqrtf(sq * (1.f / HID) + LN_EPS);
    float4 o;
    o.x = dx.x * r * g.x + bl.x;
    o.y = dx.y * r * g.y + bl.y;
    o.z = dx.z * r * g.z + bl.z;
    o.w = dx.w * r * g.w + bl.w;
    reinterpret_cast<float4*>(out + (row + 1) * HID)[lane] = o;
}

extern "C" void kernel_launch(void* const* d_in, const int* in_sizes, int n_in,
                              void* d_out, int out_size, void* d_ws, size_t ws_size,
                              hipStream_t stream) {
    const float* msg    = (const float*)d_in[0];
    const float* Wq     = (const float*)d_in[1];
    const float* Wk     = (const float*)d_in[2];
    const float* Wv     = (const float*)d_in[3];
    const float* Wr     = (const float*)d_in[4];
    const float* walpha = (const float*)d_in[5];
    const float* wbeta  = (const float*)d_in[6];
    const float* Wo     = (const float*)d_in[7];
    const float* bo     = (const float*)d_in[8];
    const float* gamma  = (const float*)d_in[9];
    const float* betaln = (const float*)d_in[10];
    const int*   seg    = (const int*)d_in[11];

    // workspace: msgb | qb | kb | vb | gq | gk | wqb wkb wvb ; act reuses msgb,
    // tmp (bf16) reuses qb. Wq/Wk/Wv pre-cast to bf16 (tiny); Wo cast fused in gemm_bt.
    char* ws = (char*)d_ws;
    const size_t nh = (size_t)N_BONDS * HID;
    size_t off = 0;
    bf16* msgb = (bf16*)(ws + off); off += nh * 2;
    bf16* qb   = (bf16*)(ws + off); off += nh * 2;
    bf16* kb   = (bf16*)(ws + off); off += nh * 2;
    bf16* vb   = (bf16*)(ws + off); off += nh * 2;
    float* gq  = (float*)(ws + off); off += (size_t)NSEG * HID * 4;
    float* gk  = (float*)(ws + off); off += (size_t)NSEG * HID * 4;
    bf16* wqb  = (bf16*)(ws + off); off += (size_t)HID * HID * 2;
    bf16* wkb  = (bf16*)(ws + off); off += (size_t)HID * HID * 2;
    bf16* wvb  = (bf16*)(ws + off); off += (size_t)HID * HID * 2;
    bf16*  act = msgb;
    bf16*  tmp = qb;

    hipMemsetAsync(gq, 0, (size_t)2 * NSEG * HID * 4, stream);
    hipMemsetAsync(d_out, 0, HID * sizeof(float), stream);

    cast_kernel<<<4096, 256, 0, stream>>>(msg, (ushort*)msgb, (int)(nh / 4));
    cast_kernel<<<32, 256, 0, stream>>>(Wq, (ushort*)wqb, HID * HID / 4);
    cast_kernel<<<32, 256, 0, stream>>>(Wk, (ushort*)wkb, HID * HID / 4);
    cast_kernel<<<32, 256, 0, stream>>>(Wv, (ushort*)wvb, HID * HID / 4);

    qkv_gemm<<<N_BONDS / 128, 256, 0, stream>>>((const ushort*)msgb,
                                                (const ushort*)wqb, (const ushort*)wkb,
                                                (const ushort*)wvb, qb, kb, vb);

    alpha_gq_kernel<<<N_BONDS / CHUNK, 256, 0, stream>>>(qb, walpha, seg, gq);
    beta_gk_kernel<<<N_BONDS / CHUNK, 256, 0, stream>>>(kb, gq, wbeta, seg, gk);

    act_mfma_kernel<<<N_BONDS * 8 / 256, 256, 0, stream>>>((const ushort*)vb, (const ushort*)qb,
                                                           gk, Wr, seg, (ushort*)act);

    dim3 gg(N_BONDS / 128, 2);
    gemm_bt<ushort, bf16><<<gg, 256, 0, stream>>>((const ushort*)act, Wo, tmp);
    ln_kernel<<<N_BONDS / 4, 256, 0, stream>>>((const ushort*)tmp, bo, gamma, betaln, (float*)d_out);
}

// Round 21
// 709.820 us; speedup vs baseline: 1.0328x; 1.0328x over previous
//
#include <hip/hip_runtime.h>
#include <hip/hip_bf16.h>
#include <type_traits>

// ---- problem constants (fixed by the reference) ----
#define N_BONDS 196608
#define HID     256
#define NSEG    4096
#define SMSCALE 0.17677669529663687f  // D^-0.5, D=32
#define LN_EPS  1e-5f
#define CHUNK   8                     // bonds per block in segment kernels

typedef __hip_bfloat16 bf16;
typedef __attribute__((ext_vector_type(8))) short short8_t;  // 8 x bf16 (4 VGPR)
typedef __attribute__((ext_vector_type(4))) float f32x4_t;

__device__ __forceinline__ float bf2f(bf16 x) { return __bfloat162float(x); }
__device__ __forceinline__ short f2bs(float f) {
    union { bf16 b; short s; } cv; cv.b = __float2bfloat16(f); return cv.s;
}
__device__ __forceinline__ float us2f(ushort u) {
    union { ushort u; bf16 b; } cv; cv.u = u; return __bfloat162float(cv.b);
}

// 32-lane-group sum inside a 64-lane wave (xor masks < 32 stay inside the head group)
__device__ __forceinline__ float gsum32(float x) {
#pragma unroll
    for (int m = 16; m >= 1; m >>= 1) x += __shfl_xor(x, m);
    return x;
}

// ---------------- f32 -> bf16 cast (x4 vectorized) ----------------
__global__ void cast_kernel(const float* __restrict__ src, ushort* __restrict__ dst, int n4) {
    int i = blockIdx.x * blockDim.x + threadIdx.x;
    const int stride = gridDim.x * blockDim.x;
    for (; i < n4; i += stride) {
        float4 v = reinterpret_cast<const float4*>(src)[i];
        union { ushort4 u; bf16 b[4]; } cv;
        cv.b[0] = __float2bfloat16(v.x);
        cv.b[1] = __float2bfloat16(v.y);
        cv.b[2] = __float2bfloat16(v.z);
        cv.b[3] = __float2bfloat16(v.w);
        reinterpret_cast<ushort4*>(dst)[i] = cv.u;
    }
}

// ---------------- pack Wq/Wk/Wv into per-lane MFMA B-fragment order --------------------------
// Fragment F = (((m*2+ch)*8+cc)*8+k0i)*64 + lane holds W[ch*128+cc*16+(lane&15)]
// [k0i*32+(lane>>4)*8 .. +8] as bf16 -- exactly the bfr each lane feeds to the MFMA.
// In qkv_gemm a B-fragment load becomes ONE coalesced 1KB wave-read (R20's direct-global read
// was a 16-row x 512B-stride gather: ~16 cache lines per instruction -> 350us @ 8.8% MfmaUtil).
__global__ __launch_bounds__(256) void pack_w_kernel(const float* __restrict__ Wq,
                                                     const float* __restrict__ Wk,
                                                     const float* __restrict__ Wv,
                                                     ushort* __restrict__ Wpack) {
    const int f = blockIdx.x * 256 + threadIdx.x;   // 24576 fragments
    const int lane = f & 63;
    const int k0i = (f >> 6) & 7;
    const int cc = (f >> 9) & 7;
    const int ch = (f >> 12) & 1;
    const int m = f >> 13;
    const float* W = (m == 0) ? Wq : (m == 1) ? Wk : Wv;
    const int lr = lane & 15, lk = lane >> 4;
    const float* wp = W + (ch * 128 + cc * 16 + lr) * HID + k0i * 32 + lk * 8;
    float4 w0 = *reinterpret_cast<const float4*>(wp);
    float4 w1 = *reinterpret_cast<const float4*>(wp + 4);
    short8_t o;
    o[0] = f2bs(w0.x); o[1] = f2bs(w0.y); o[2] = f2bs(w0.z); o[3] = f2bs(w0.w);
    o[4] = f2bs(w1.x); o[5] = f2bs(w1.y); o[6] = f2bs(w1.z); o[7] = f2bs(w1.w);
    *reinterpret_cast<short8_t*>(Wpack + (long)f * 8) = o;
}

// ---------------- GEMM: C[n,j] = sum_i A[n,i] * W[j,i]  (torch Linear, B^T form) ----------------
// VERBATIM from R13 (known-pass). W f32 -> bf16 during LDS staging; A bf16. Used for W_o.
template <typename AT, typename OutT>
__global__ __launch_bounds__(256, 2) void gemm_bt(const AT* __restrict__ A,
                                                  const float* __restrict__ W,
                                                  OutT* __restrict__ C) {
    __shared__ __align__(16) char lds[128 * 512];
    const int t = threadIdx.x;
    const int colhalf = blockIdx.y;
#pragma unroll
    for (int it = 0; it < 16; ++it) {
        int c = it * 256 + t;
        int j = c >> 5, kc = c & 31;
        const float* wp = W + ((colhalf << 7) + j) * HID + (kc << 3);
        float4 w0 = *reinterpret_cast<const float4*>(wp);
        float4 w1 = *reinterpret_cast<const float4*>(wp + 4);
        union { uint4 u; short s[8]; } cv;
        cv.s[0] = f2bs(w0.x); cv.s[1] = f2bs(w0.y); cv.s[2] = f2bs(w0.z); cv.s[3] = f2bs(w0.w);
        cv.s[4] = f2bs(w1.x); cv.s[5] = f2bs(w1.y); cv.s[6] = f2bs(w1.z); cv.s[7] = f2bs(w1.w);
        *reinterpret_cast<uint4*>(lds + j * 512 + ((kc << 4) ^ ((j & 7) << 4))) = cv.u;
    }
    __syncthreads();

    const int wave = t >> 6, lane = t & 63;
    const int lr = lane & 15, lk = lane >> 4;
    const long rowbase = (long)blockIdx.x * 128 + wave * 32;

    f32x4_t acc[2][8];
#pragma unroll
    for (int r = 0; r < 2; ++r)
#pragma unroll
        for (int cc = 0; cc < 8; ++cc) acc[r][cc] = (f32x4_t){0.f, 0.f, 0.f, 0.f};

    const AT* a0 = A + (rowbase + lr) * HID;
    const AT* a1 = a0 + 16 * HID;
#pragma unroll
    for (int k0 = 0; k0 < HID; k0 += 32) {
        const int koff = k0 + lk * 8;
        short8_t af0, af1;
        if constexpr (std::is_same_v<AT, float>) {
            float4 x0 = *reinterpret_cast<const float4*>(a0 + koff);
            float4 x1 = *reinterpret_cast<const float4*>(a0 + koff + 4);
            float4 y0 = *reinterpret_cast<const float4*>(a1 + koff);
            float4 y1 = *reinterpret_cast<const float4*>(a1 + koff + 4);
            af0[0] = f2bs(x0.x); af0[1] = f2bs(x0.y); af0[2] = f2bs(x0.z); af0[3] = f2bs(x0.w);
            af0[4] = f2bs(x1.x); af0[5] = f2bs(x1.y); af0[6] = f2bs(x1.z); af0[7] = f2bs(x1.w);
            af1[0] = f2bs(y0.x); af1[1] = f2bs(y0.y); af1[2] = f2bs(y0.z); af1[3] = f2bs(y0.w);
            af1[4] = f2bs(y1.x); af1[5] = f2bs(y1.y); af1[6] = f2bs(y1.z); af1[7] = f2bs(y1.w);
        } else {
            af0 = *reinterpret_cast<const short8_t*>(a0 + koff);
            af1 = *reinterpret_cast<const short8_t*>(a1 + koff);
        }
#pragma unroll
        for (int cc = 0; cc < 8; ++cc) {
            const int j = cc * 16 + lr;
            short8_t bfr = *reinterpret_cast<const short8_t*>(
                lds + j * 512 + (((k0 << 1) + (lk << 4)) ^ ((j & 7) << 4)));
            acc[0][cc] = __builtin_amdgcn_mfma_f32_16x16x32_bf16(af0, bfr, acc[0][cc], 0, 0, 0);
            acc[1][cc] = __builtin_amdgcn_mfma_f32_16x16x32_bf16(af1, bfr, acc[1][cc], 0, 0, 0);
        }
    }
    // C/D layout (verified m89): col = lane&15, row = (lane>>4)*4 + reg
#pragma unroll
    for (int r = 0; r < 2; ++r) {
#pragma unroll
        for (int cc = 0; cc < 8; ++cc) {
            const int col = (colhalf << 7) + cc * 16 + lr;
#pragma unroll
            for (int reg = 0; reg < 4; ++reg) {
                const long row = rowbase + r * 16 + lk * 4 + reg;
                const float v = acc[r][cc][reg];
                if constexpr (sizeof(OutT) == 2) C[row * HID + col] = __float2bfloat16(v);
                else                             C[row * HID + col] = v;
            }
        }
    }
}

// ---------------- merged QKV: A-tile in LDS (read once) + packed coalesced W fragments -------
// A staging + LDS read path VERBATIM from R20 (passed; FETCH 54MB). B-fragment read is now a
// single coalesced 1KB wave-load from Wpack (L2-resident 384KB, shared by all 4 waves).
__global__ __launch_bounds__(256, 2) void qkv_gemm(const ushort* __restrict__ A,
                                                   const ushort* __restrict__ Wpack,
                                                   bf16* __restrict__ Q,
                                                   bf16* __restrict__ K,
                                                   bf16* __restrict__ V) {
    __shared__ __align__(16) char lds[128 * 512];
    const int t = threadIdx.x;
    const long row0 = (long)blockIdx.x * 128;

    // stage A tile: 128 rows x 32 chunks of 8 bf16 (no cast -- already bf16)
#pragma unroll
    for (int it = 0; it < 16; ++it) {
        int c = it * 256 + t;
        int j = c >> 5, kc = c & 31;
        uint4 val = *reinterpret_cast<const uint4*>(A + (row0 + j) * HID + (kc << 3));
        *reinterpret_cast<uint4*>(lds + j * 512 + ((kc << 4) ^ ((j & 7) << 4))) = val;
    }
    __syncthreads();

    const int wave = t >> 6, lane = t & 63;
    const int lr = lane & 15, lk = lane >> 4;
    const int r0 = wave * 32 + lr;        // local A row for af0 ((r0&7) == (lr&7))
    const int r1 = r0 + 16;               // local A row for af1 (same &7)

#pragma unroll
    for (int m = 0; m < 3; ++m) {
        bf16* C = (m == 0) ? Q : (m == 1) ? K : V;
#pragma unroll
        for (int ch = 0; ch < 2; ++ch) {
            const ushort* wp = Wpack + ((long)(m * 2 + ch) << 12) * 8;  // (m*2+ch)*4096 frags... *8 shorts
            f32x4_t acc[2][8];
#pragma unroll
            for (int r = 0; r < 2; ++r)
#pragma unroll
                for (int cc = 0; cc < 8; ++cc) acc[r][cc] = (f32x4_t){0.f, 0.f, 0.f, 0.f};

#pragma unroll
            for (int k0 = 0; k0 < HID; k0 += 32) {
                const int k0i = k0 >> 5;
                short8_t af0 = *reinterpret_cast<const short8_t*>(
                    lds + r0 * 512 + (((k0 << 1) + (lk << 4)) ^ ((lr & 7) << 4)));
                short8_t af1 = *reinterpret_cast<const short8_t*>(
                    lds + r1 * 512 + (((k0 << 1) + (lk << 4)) ^ ((lr & 7) << 4)));
#pragma unroll
                for (int cc = 0; cc < 8; ++cc) {
                    short8_t bfr = *reinterpret_cast<const short8_t*>(
                        wp + (((cc << 3) + k0i) * 64 + lane) * 8);
                    acc[0][cc] = __builtin_amdgcn_mfma_f32_16x16x32_bf16(af0, bfr, acc[0][cc], 0, 0, 0);
                    acc[1][cc] = __builtin_amdgcn_mfma_f32_16x16x32_bf16(af1, bfr, acc[1][cc], 0, 0, 0);
                }
            }
#pragma unroll
            for (int r = 0; r < 2; ++r) {
#pragma unroll
                for (int cc = 0; cc < 8; ++cc) {
                    const int col = (ch << 7) + cc * 16 + lr;
#pragma unroll
                    for (int reg = 0; reg < 4; ++reg) {
                        const long row = row0 + wave * 32 + r * 16 + lk * 4 + reg;
                        C[row * HID + col] = __float2bfloat16(acc[r][cc][reg]);
                    }
                }
            }
        }
    }
}

// ---------------- alpha = softmax_d(q*w_alpha*scale); gq = segment_sum(alpha*q) ----------------
// VERBATIM from R10 (known-pass).
__global__ __launch_bounds__(256) void alpha_gq_kernel(const bf16* __restrict__ qb,
                                                       const float* __restrict__ w_alpha,
                                                       const int* __restrict__ seg,
                                                       float* __restrict__ gq) {
    const int j = threadIdx.x;
    const float wa = w_alpha[j & 31] * SMSCALE;
    const long n0 = (long)blockIdx.x * CHUNK;
    float acc = 0.f;
    int cur = -1;
    for (int i = 0; i < CHUNK; ++i) {
        const long n = n0 + i;
        const int s = seg[n];
        const float qv = bf2f(qb[n * HID + j]);
        const float e = __expf(qv * wa);
        const float ssum = gsum32(e);
        const float alpha = e / ssum;
        if (s != cur) {
            if (cur >= 0) atomicAdd(&gq[(long)cur * HID + j], acc);
            acc = 0.f;
            cur = s;
        }
        acc += alpha * qv;
    }
    atomicAdd(&gq[(long)cur * HID + j], acc);
}

// ---------------- p = gq[seg]*k; beta = softmax_d(p*w_beta*scale); gk = segment_sum(beta*p) ----
// VERBATIM from R10 (known-pass).
__global__ __launch_bounds__(256) void beta_gk_kernel(const bf16* __restrict__ kb,
                                                      const float* __restrict__ gq,
                                                      const float* __restrict__ w_beta,
                                                      const int* __restrict__ seg,
                                                      float* __restrict__ gk) {
    const int j = threadIdx.x;
    const float wb = w_beta[j & 31] * SMSCALE;
    const long n0 = (long)blockIdx.x * CHUNK;
    float acc = 0.f;
    int cur = -1;
    for (int i = 0; i < CHUNK; ++i) {
        const long n = n0 + i;
        const int s = seg[n];
        const float kv = bf2f(kb[n * HID + j]);
        const float p = gq[(long)s * HID + j] * kv;
        const float e = __expf(p * wb);
        const float ssum = gsum32(e);
        const float beta = e / ssum;
        if (s != cur) {
            if (cur >= 0) atomicAdd(&gk[(long)cur * HID + j], acc);
            acc = 0.f;
            cur = s;
        }
        acc += beta * p;
    }
    atomicAdd(&gk[(long)cur * HID + j], acc);
}

// ---------------- act = relu((gk[seg]*v) @ W_r^T per head + q) via bf16 hi/lo MFMA -----------
// VERBATIM from R12/R13 (known-pass).
__global__ __launch_bounds__(256) void act_mfma_kernel(const ushort* __restrict__ vb,
                                                       const ushort* __restrict__ qb,
                                                       const float* __restrict__ gk,
                                                       const float* __restrict__ Wr,
                                                       const int* __restrict__ seg,
                                                       ushort* __restrict__ act) {
    const int t = threadIdx.x;
    const int wave = t >> 6, lane = t & 63;
    const int lr = lane & 15, lk = lane >> 4;

    short8_t bhi[2], blo[2];
#pragma unroll
    for (int ct = 0; ct < 2; ++ct) {
        const float* wr = Wr + (ct * 16 + lr) * 32 + lk * 8;
#pragma unroll
        for (int e = 0; e < 8; ++e) {
            const float w = wr[e];
            const short h = f2bs(w);
            bhi[ct][e] = h;
            blo[ct][e] = f2bs(w - us2f((ushort)h));
        }
    }

    const long rowblock = (long)blockIdx.x * 256 + wave * 64;
#pragma unroll
    for (int rt = 0; rt < 4; ++rt) {
        const long rtbase = rowblock + rt * 16;
        const long arow = rtbase + lr;
        const int n = (int)(arow >> 3), h = (int)(arow & 7);
        const int sid = seg[n];
        short8_t v8 = *reinterpret_cast<const short8_t*>(vb + arow * 32 + lk * 8);
        const float* gp = gk + (long)sid * HID + h * 32 + lk * 8;
        float4 g0 = *reinterpret_cast<const float4*>(gp);
        float4 g1 = *reinterpret_cast<const float4*>(gp + 4);
        float kvi[8];
        kvi[0] = g0.x * us2f((ushort)v8[0]);
        kvi[1] = g0.y * us2f((ushort)v8[1]);
        kvi[2] = g0.z * us2f((ushort)v8[2]);
        kvi[3] = g0.w * us2f((ushort)v8[3]);
        kvi[4] = g1.x * us2f((ushort)v8[4]);
        kvi[5] = g1.y * us2f((ushort)v8[5]);
        kvi[6] = g1.z * us2f((ushort)v8[6]);
        kvi[7] = g1.w * us2f((ushort)v8[7]);
        short8_t ahi, alo;
#pragma unroll
        for (int e = 0; e < 8; ++e) {
            const short hh = f2bs(kvi[e]);
            ahi[e] = hh;
            alo[e] = f2bs(kvi[e] - us2f((ushort)hh));
        }
#pragma unroll
        for (int ct = 0; ct < 2; ++ct) {
            f32x4_t c = (f32x4_t){0.f, 0.f, 0.f, 0.f};
            c = __builtin_amdgcn_mfma_f32_16x16x32_bf16(ahi, bhi[ct], c, 0, 0, 0);
            c = __builtin_amdgcn_mfma_f32_16x16x32_bf16(alo, bhi[ct], c, 0, 0, 0);
            c = __builtin_amdgcn_mfma_f32_16x16x32_bf16(ahi, blo[ct], c, 0, 0, 0);
#pragma unroll
            for (int reg = 0; reg < 4; ++reg) {
                const long row = rtbase + lk * 4 + reg;
                const long idx = row * 32 + ct * 16 + lr;
                act[idx] = (ushort)f2bs(fmaxf(c[reg] + us2f(qb[idx]), 0.f));
            }
        }
    }
}

// ---------------- LayerNorm: one wave per row, bf16 tmp input, write d_out row n+1 ----------
// VERBATIM from R11/R13 (known-pass).
__global__ __launch_bounds__(256) void ln_kernel(const ushort* __restrict__ tmp,
                                                 const float* __restrict__ b_o,
                                                 const float* __restrict__ gamma,
                                                 const float* __restrict__ beta_ln,
                                                 float* __restrict__ out) {
    const int wave = threadIdx.x >> 6, lane = threadIdx.x & 63;
    const long row = (long)blockIdx.x * 4 + wave;
    const float4 bo = reinterpret_cast<const float4*>(b_o)[lane];
    const float4 g = reinterpret_cast<const float4*>(gamma)[lane];
    const float4 bl = reinterpret_cast<const float4*>(beta_ln)[lane];
    const ushort4 xr = reinterpret_cast<const ushort4*>(tmp + row * HID)[lane];
    float4 x = {us2f(xr.x) + bo.x, us2f(xr.y) + bo.y, us2f(xr.z) + bo.z, us2f(xr.w) + bo.w};
    float s = x.x + x.y + x.z + x.w;
#pragma unroll
    for (int m = 32; m >= 1; m >>= 1) s += __shfl_xor(s, m);
    const float mu = s * (1.f / HID);
    float4 dx = {x.x - mu, x.y - mu, x.z - mu, x.w - mu};
    float sq = dx.x * dx.x + dx.y * dx.y + dx.z * dx.z + dx.w * dx.w;
#pragma unroll
    for (int m = 32; m >= 1; m >>= 1) sq += __shfl_xor(sq, m);
    const float r = rsqrtf(sq * (1.f / HID) + LN_EPS);
    float4 o;
    o.x = dx.x * r * g.x + bl.x;
    o.y = dx.y * r * g.y + bl.y;
    o.z = dx.z * r * g.z + bl.z;
    o.w = dx.w * r * g.w + bl.w;
    reinterpret_cast<float4*>(out + (row + 1) * HID)[lane] = o;
}

extern "C" void kernel_launch(void* const* d_in, const int* in_sizes, int n_in,
                              void* d_out, int out_size, void* d_ws, size_t ws_size,
                              hipStream_t stream) {
    const float* msg    = (const float*)d_in[0];
    const float* Wq     = (const float*)d_in[1];
    const float* Wk     = (const float*)d_in[2];
    const float* Wv     = (const float*)d_in[3];
    const float* Wr     = (const float*)d_in[4];
    const float* walpha = (const float*)d_in[5];
    const float* wbeta  = (const float*)d_in[6];
    const float* Wo     = (const float*)d_in[7];
    const float* bo     = (const float*)d_in[8];
    const float* gamma  = (const float*)d_in[9];
    const float* betaln = (const float*)d_in[10];
    const int*   seg    = (const int*)d_in[11];

    // workspace: msgb | qb | kb | vb | gq | gk | Wpack ; act reuses msgb, tmp reuses qb.
    char* ws = (char*)d_ws;
    const size_t nh = (size_t)N_BONDS * HID;
    size_t off = 0;
    bf16* msgb = (bf16*)(ws + off); off += nh * 2;
    bf16* qb   = (bf16*)(ws + off); off += nh * 2;
    bf16* kb   = (bf16*)(ws + off); off += nh * 2;
    bf16* vb   = (bf16*)(ws + off); off += nh * 2;
    float* gq  = (float*)(ws + off); off += (size_t)NSEG * HID * 4;
    float* gk  = (float*)(ws + off); off += (size_t)NSEG * HID * 4;
    ushort* wpk = (ushort*)(ws + off); off += (size_t)3 * HID * HID * 2;
    bf16*  act = msgb;
    bf16*  tmp = qb;

    hipMemsetAsync(gq, 0, (size_t)2 * NSEG * HID * 4, stream);
    hipMemsetAsync(d_out, 0, HID * sizeof(float), stream);

    cast_kernel<<<4096, 256, 0, stream>>>(msg, (ushort*)msgb, (int)(nh / 4));
    pack_w_kernel<<<96, 256, 0, stream>>>(Wq, Wk, Wv, wpk);

    qkv_gemm<<<N_BONDS / 128, 256, 0, stream>>>((const ushort*)msgb, wpk, qb, kb, vb);

    alpha_gq_kernel<<<N_BONDS / CHUNK, 256, 0, stream>>>(qb, walpha, seg, gq);
    beta_gk_kernel<<<N_BONDS / CHUNK, 256, 0, stream>>>(kb, gq, wbeta, seg, gk);

    act_mfma_kernel<<<N_BONDS * 8 / 256, 256, 0, stream>>>((const ushort*)vb, (const ushort*)qb,
                                                           gk, Wr, seg, (ushort*)act);

    dim3 gg(N_BONDS / 128, 2);
    gemm_bt<ushort, bf16><<<gg, 256, 0, stream>>>((const ushort*)act, Wo, tmp);
    ln_kernel<<<N_BONDS / 4, 256, 0, stream>>>((const ushort*)tmp, bo, gamma, betaln, (float*)d_out);
}

// Round 22
// 590.129 us; speedup vs baseline: 1.2422x; 1.2028x over previous
//
#include <hip/hip_runtime.h>
#include <hip/hip_bf16.h>
#include <type_traits>

// ---- problem constants (fixed by the reference) ----
#define N_BONDS 196608
#define HID     256
#define NSEG    4096
#define SMSCALE 0.17677669529663687f  // D^-0.5, D=32
#define LN_EPS  1e-5f
#define CHUNK   8                     // bonds per block in segment kernels

typedef __hip_bfloat16 bf16;
typedef __attribute__((ext_vector_type(8))) short short8_t;  // 8 x bf16 (4 VGPR)
typedef __attribute__((ext_vector_type(4))) float f32x4_t;

__device__ __forceinline__ float bf2f(bf16 x) { return __bfloat162float(x); }
__device__ __forceinline__ short f2bs(float f) {
    union { bf16 b; short s; } cv; cv.b = __float2bfloat16(f); return cv.s;
}
__device__ __forceinline__ float us2f(ushort u) {
    union { ushort u; bf16 b; } cv; cv.u = u; return __bfloat162float(cv.b);
}

// 32-lane-group sum inside a 64-lane wave (xor masks < 32 stay inside the head group)
__device__ __forceinline__ float gsum32(float x) {
#pragma unroll
    for (int m = 16; m >= 1; m >>= 1) x += __shfl_xor(x, m);
    return x;
}

// ---------------- f32 -> bf16 cast (x4 vectorized) ----------------
__global__ void cast_kernel(const float* __restrict__ src, ushort* __restrict__ dst, int n4) {
    int i = blockIdx.x * blockDim.x + threadIdx.x;
    const int stride = gridDim.x * blockDim.x;
    for (; i < n4; i += stride) {
        float4 v = reinterpret_cast<const float4*>(src)[i];
        union { ushort4 u; bf16 b[4]; } cv;
        cv.b[0] = __float2bfloat16(v.x);
        cv.b[1] = __float2bfloat16(v.y);
        cv.b[2] = __float2bfloat16(v.z);
        cv.b[3] = __float2bfloat16(v.w);
        reinterpret_cast<ushort4*>(dst)[i] = cv.u;
    }
}

// ---------------- GEMM: C[n,j] = sum_i A[n,i] * W[j,i]  (torch Linear, B^T form) ----------------
// VERBATIM from R13/R17 (known-pass). W f32 -> bf16 during LDS staging; A bf16. Single LDS
// stage, no in-kernel restage (restage+acc-across-barrier is the R14/R15-cursed pattern).
template <typename AT, typename OutT>
__global__ __launch_bounds__(256, 2) void gemm_bt(const AT* __restrict__ A,
                                                  const float* __restrict__ W,
                                                  OutT* __restrict__ C) {
    __shared__ __align__(16) char lds[128 * 512];
    const int t = threadIdx.x;
    const int colhalf = blockIdx.y;
#pragma unroll
    for (int it = 0; it < 16; ++it) {
        int c = it * 256 + t;
        int j = c >> 5, kc = c & 31;
        const float* wp = W + ((colhalf << 7) + j) * HID + (kc << 3);
        float4 w0 = *reinterpret_cast<const float4*>(wp);
        float4 w1 = *reinterpret_cast<const float4*>(wp + 4);
        union { uint4 u; short s[8]; } cv;
        cv.s[0] = f2bs(w0.x); cv.s[1] = f2bs(w0.y); cv.s[2] = f2bs(w0.z); cv.s[3] = f2bs(w0.w);
        cv.s[4] = f2bs(w1.x); cv.s[5] = f2bs(w1.y); cv.s[6] = f2bs(w1.z); cv.s[7] = f2bs(w1.w);
        *reinterpret_cast<uint4*>(lds + j * 512 + ((kc << 4) ^ ((j & 7) << 4))) = cv.u;
    }
    __syncthreads();

    const int wave = t >> 6, lane = t & 63;
    const int lr = lane & 15, lk = lane >> 4;
    const long rowbase = (long)blockIdx.x * 128 + wave * 32;

    f32x4_t acc[2][8];
#pragma unroll
    for (int r = 0; r < 2; ++r)
#pragma unroll
        for (int cc = 0; cc < 8; ++cc) acc[r][cc] = (f32x4_t){0.f, 0.f, 0.f, 0.f};

    const AT* a0 = A + (rowbase + lr) * HID;
    const AT* a1 = a0 + 16 * HID;
#pragma unroll
    for (int k0 = 0; k0 < HID; k0 += 32) {
        const int koff = k0 + lk * 8;
        short8_t af0, af1;
        if constexpr (std::is_same_v<AT, float>) {
            float4 x0 = *reinterpret_cast<const float4*>(a0 + koff);
            float4 x1 = *reinterpret_cast<const float4*>(a0 + koff + 4);
            float4 y0 = *reinterpret_cast<const float4*>(a1 + koff);
            float4 y1 = *reinterpret_cast<const float4*>(a1 + koff + 4);
            af0[0] = f2bs(x0.x); af0[1] = f2bs(x0.y); af0[2] = f2bs(x0.z); af0[3] = f2bs(x0.w);
            af0[4] = f2bs(x1.x); af0[5] = f2bs(x1.y); af0[6] = f2bs(x1.z); af0[7] = f2bs(x1.w);
            af1[0] = f2bs(y0.x); af1[1] = f2bs(y0.y); af1[2] = f2bs(y0.z); af1[3] = f2bs(y0.w);
            af1[4] = f2bs(y1.x); af1[5] = f2bs(y1.y); af1[6] = f2bs(y1.z); af1[7] = f2bs(y1.w);
        } else {
            af0 = *reinterpret_cast<const short8_t*>(a0 + koff);
            af1 = *reinterpret_cast<const short8_t*>(a1 + koff);
        }
#pragma unroll
        for (int cc = 0; cc < 8; ++cc) {
            const int j = cc * 16 + lr;
            short8_t bfr = *reinterpret_cast<const short8_t*>(
                lds + j * 512 + (((k0 << 1) + (lk << 4)) ^ ((j & 7) << 4)));
            acc[0][cc] = __builtin_amdgcn_mfma_f32_16x16x32_bf16(af0, bfr, acc[0][cc], 0, 0, 0);
            acc[1][cc] = __builtin_amdgcn_mfma_f32_16x16x32_bf16(af1, bfr, acc[1][cc], 0, 0, 0);
        }
    }
    // C/D layout (verified m89): col = lane&15, row = (lane>>4)*4 + reg
#pragma unroll
    for (int r = 0; r < 2; ++r) {
#pragma unroll
        for (int cc = 0; cc < 8; ++cc) {
            const int col = (colhalf << 7) + cc * 16 + lr;
#pragma unroll
            for (int reg = 0; reg < 4; ++reg) {
                const long row = rowbase + r * 16 + lk * 4 + reg;
                const float v = acc[r][cc][reg];
                if constexpr (sizeof(OutT) == 2) C[row * HID + col] = __float2bfloat16(v);
                else                             C[row * HID + col] = v;
            }
        }
    }
}

// ---------------- merged QKV: grid.y = 6 -> (which, colhalf); body identical to gemm_bt ------
// VERBATIM from R17 (best-verified: 184us, pass 0.03125). Wave-uniform W/C select, single
// 64KB W-half LDS stage. Five alternative qkv schedules (R18-R21) all regressed: quarter-tile
// raised traffic (L3 couldn't absorb 12-pass A re-streams), A-in-LDS collapsed MFMA util to
// ~9% (6 serial phases at 2 blocks/CU can't hide latency). This is the empirical optimum.
__global__ __launch_bounds__(256, 2) void qkv_gemm(const ushort* __restrict__ A,
                                                   const float* __restrict__ Wq,
                                                   const float* __restrict__ Wk,
                                                   const float* __restrict__ Wv,
                                                   bf16* __restrict__ Q,
                                                   bf16* __restrict__ K,
                                                   bf16* __restrict__ V) {
    __shared__ __align__(16) char lds[128 * 512];
    const int t = threadIdx.x;
    const int which = blockIdx.y >> 1;
    const int colhalf = blockIdx.y & 1;
    const float* W = (which == 0) ? Wq : (which == 1) ? Wk : Wv;
    bf16* C = (which == 0) ? Q : (which == 1) ? K : V;

#pragma unroll
    for (int it = 0; it < 16; ++it) {
        int c = it * 256 + t;
        int j = c >> 5, kc = c & 31;
        const float* wp = W + ((colhalf << 7) + j) * HID + (kc << 3);
        float4 w0 = *reinterpret_cast<const float4*>(wp);
        float4 w1 = *reinterpret_cast<const float4*>(wp + 4);
        union { uint4 u; short s[8]; } cv;
        cv.s[0] = f2bs(w0.x); cv.s[1] = f2bs(w0.y); cv.s[2] = f2bs(w0.z); cv.s[3] = f2bs(w0.w);
        cv.s[4] = f2bs(w1.x); cv.s[5] = f2bs(w1.y); cv.s[6] = f2bs(w1.z); cv.s[7] = f2bs(w1.w);
        *reinterpret_cast<uint4*>(lds + j * 512 + ((kc << 4) ^ ((j & 7) << 4))) = cv.u;
    }
    __syncthreads();

    const int wave = t >> 6, lane = t & 63;
    const int lr = lane & 15, lk = lane >> 4;
    const long rowbase = (long)blockIdx.x * 128 + wave * 32;

    f32x4_t acc[2][8];
#pragma unroll
    for (int r = 0; r < 2; ++r)
#pragma unroll
        for (int cc = 0; cc < 8; ++cc) acc[r][cc] = (f32x4_t){0.f, 0.f, 0.f, 0.f};

    const ushort* a0 = A + (rowbase + lr) * HID;
    const ushort* a1 = a0 + 16 * HID;
#pragma unroll
    for (int k0 = 0; k0 < HID; k0 += 32) {
        const int koff = k0 + lk * 8;
        short8_t af0 = *reinterpret_cast<const short8_t*>(a0 + koff);
        short8_t af1 = *reinterpret_cast<const short8_t*>(a1 + koff);
#pragma unroll
        for (int cc = 0; cc < 8; ++cc) {
            const int j = cc * 16 + lr;
            short8_t bfr = *reinterpret_cast<const short8_t*>(
                lds + j * 512 + (((k0 << 1) + (lk << 4)) ^ ((j & 7) << 4)));
            acc[0][cc] = __builtin_amdgcn_mfma_f32_16x16x32_bf16(af0, bfr, acc[0][cc], 0, 0, 0);
            acc[1][cc] = __builtin_amdgcn_mfma_f32_16x16x32_bf16(af1, bfr, acc[1][cc], 0, 0, 0);
        }
    }
#pragma unroll
    for (int r = 0; r < 2; ++r) {
#pragma unroll
        for (int cc = 0; cc < 8; ++cc) {
            const int col = (colhalf << 7) + cc * 16 + lr;
#pragma unroll
            for (int reg = 0; reg < 4; ++reg) {
                const long row = rowbase + r * 16 + lk * 4 + reg;
                C[row * HID + col] = __float2bfloat16(acc[r][cc][reg]);
            }
        }
    }
}

// ---------------- alpha = softmax_d(q*w_alpha*scale); gq = segment_sum(alpha*q) ----------------
// VERBATIM from R10 (known-pass). One thread per (h,d); one atomic per segment flush;
// short serial chain (CHUNK=8); no-max softmax (|x|<=~3, f32-exact-safe, shift-invariant).
__global__ __launch_bounds__(256) void alpha_gq_kernel(const bf16* __restrict__ qb,
                                                       const float* __restrict__ w_alpha,
                                                       const int* __restrict__ seg,
                                                       float* __restrict__ gq) {
    const int j = threadIdx.x;
    const float wa = w_alpha[j & 31] * SMSCALE;
    const long n0 = (long)blockIdx.x * CHUNK;
    float acc = 0.f;
    int cur = -1;
    for (int i = 0; i < CHUNK; ++i) {
        const long n = n0 + i;
        const int s = seg[n];
        const float qv = bf2f(qb[n * HID + j]);
        const float e = __expf(qv * wa);
        const float ssum = gsum32(e);
        const float alpha = e / ssum;
        if (s != cur) {
            if (cur >= 0) atomicAdd(&gq[(long)cur * HID + j], acc);
            acc = 0.f;
            cur = s;
        }
        acc += alpha * qv;
    }
    atomicAdd(&gq[(long)cur * HID + j], acc);
}

// ---------------- p = gq[seg]*k; beta = softmax_d(p*w_beta*scale); gk = segment_sum(beta*p) ----
// VERBATIM from R10 (known-pass).
__global__ __launch_bounds__(256) void beta_gk_kernel(const bf16* __restrict__ kb,
                                                      const float* __restrict__ gq,
                                                      const float* __restrict__ w_beta,
                                                      const int* __restrict__ seg,
                                                      float* __restrict__ gk) {
    const int j = threadIdx.x;
    const float wb = w_beta[j & 31] * SMSCALE;
    const long n0 = (long)blockIdx.x * CHUNK;
    float acc = 0.f;
    int cur = -1;
    for (int i = 0; i < CHUNK; ++i) {
        const long n = n0 + i;
        const int s = seg[n];
        const float kv = bf2f(kb[n * HID + j]);
        const float p = gq[(long)s * HID + j] * kv;
        const float e = __expf(p * wb);
        const float ssum = gsum32(e);
        const float beta = e / ssum;
        if (s != cur) {
            if (cur >= 0) atomicAdd(&gk[(long)cur * HID + j], acc);
            acc = 0.f;
            cur = s;
        }
        acc += beta * p;
    }
    atomicAdd(&gk[(long)cur * HID + j], acc);
}

// ---------------- act = relu((gk[seg]*v) @ W_r^T per head + q) via bf16 hi/lo MFMA -----------
// VERBATIM from R12/R13/R17 (known-pass). Compensated bf16 split (hi=bf16(x), lo=bf16(x-hi);
// bf16 has full f32 exponent range -> residuals never flush): dot = hi*hi + lo*hi + hi*lo,
// effective input precision ~2^-17, invisible vs the 0.031 bf16-storage floor.
__global__ __launch_bounds__(256) void act_mfma_kernel(const ushort* __restrict__ vb,
                                                       const ushort* __restrict__ qb,
                                                       const float* __restrict__ gk,
                                                       const float* __restrict__ Wr,
                                                       const int* __restrict__ seg,
                                                       ushort* __restrict__ act) {
    const int t = threadIdx.x;
    const int wave = t >> 6, lane = t & 63;
    const int lr = lane & 15, lk = lane >> 4;

    short8_t bhi[2], blo[2];
#pragma unroll
    for (int ct = 0; ct < 2; ++ct) {
        const float* wr = Wr + (ct * 16 + lr) * 32 + lk * 8;
#pragma unroll
        for (int e = 0; e < 8; ++e) {
            const float w = wr[e];
            const short h = f2bs(w);
            bhi[ct][e] = h;
            blo[ct][e] = f2bs(w - us2f((ushort)h));
        }
    }

    const long rowblock = (long)blockIdx.x * 256 + wave * 64;
#pragma unroll
    for (int rt = 0; rt < 4; ++rt) {
        const long rtbase = rowblock + rt * 16;
        const long arow = rtbase + lr;
        const int n = (int)(arow >> 3), h = (int)(arow & 7);
        const int sid = seg[n];
        short8_t v8 = *reinterpret_cast<const short8_t*>(vb + arow * 32 + lk * 8);
        const float* gp = gk + (long)sid * HID + h * 32 + lk * 8;
        float4 g0 = *reinterpret_cast<const float4*>(gp);
        float4 g1 = *reinterpret_cast<const float4*>(gp + 4);
        float kvi[8];
        kvi[0] = g0.x * us2f((ushort)v8[0]);
        kvi[1] = g0.y * us2f((ushort)v8[1]);
        kvi[2] = g0.z * us2f((ushort)v8[2]);
        kvi[3] = g0.w * us2f((ushort)v8[3]);
        kvi[4] = g1.x * us2f((ushort)v8[4]);
        kvi[5] = g1.y * us2f((ushort)v8[5]);
        kvi[6] = g1.z * us2f((ushort)v8[6]);
        kvi[7] = g1.w * us2f((ushort)v8[7]);
        short8_t ahi, alo;
#pragma unroll
        for (int e = 0; e < 8; ++e) {
            const short hh = f2bs(kvi[e]);
            ahi[e] = hh;
            alo[e] = f2bs(kvi[e] - us2f((ushort)hh));
        }
#pragma unroll
        for (int ct = 0; ct < 2; ++ct) {
            f32x4_t c = (f32x4_t){0.f, 0.f, 0.f, 0.f};
            c = __builtin_amdgcn_mfma_f32_16x16x32_bf16(ahi, bhi[ct], c, 0, 0, 0);
            c = __builtin_amdgcn_mfma_f32_16x16x32_bf16(alo, bhi[ct], c, 0, 0, 0);
            c = __builtin_amdgcn_mfma_f32_16x16x32_bf16(ahi, blo[ct], c, 0, 0, 0);
#pragma unroll
            for (int reg = 0; reg < 4; ++reg) {
                const long row = rtbase + lk * 4 + reg;
                const long idx = row * 32 + ct * 16 + lr;
                act[idx] = (ushort)f2bs(fmaxf(c[reg] + us2f(qb[idx]), 0.f));
            }
        }
    }
}

// ---------------- LayerNorm: one wave per row, bf16 tmp input, write d_out row n+1 ----------
// VERBATIM from R11/R13/R17 (known-pass). Fusing this into the W_o GEMM is correctness-cursed
// on this toolchain (3 independent implementations failed: R14/R15 + the R2-R5 cluster).
__global__ __launch_bounds__(256) void ln_kernel(const ushort* __restrict__ tmp,
                                                 const float* __restrict__ b_o,
                                                 const float* __restrict__ gamma,
                                                 const float* __restrict__ beta_ln,
                                                 float* __restrict__ out) {
    const int wave = threadIdx.x >> 6, lane = threadIdx.x & 63;
    const long row = (long)blockIdx.x * 4 + wave;
    const float4 bo = reinterpret_cast<const float4*>(b_o)[lane];
    const float4 g = reinterpret_cast<const float4*>(gamma)[lane];
    const float4 bl = reinterpret_cast<const float4*>(beta_ln)[lane];
    const ushort4 xr = reinterpret_cast<const ushort4*>(tmp + row * HID)[lane];
    float4 x = {us2f(xr.x) + bo.x, us2f(xr.y) + bo.y, us2f(xr.z) + bo.z, us2f(xr.w) + bo.w};
    float s = x.x + x.y + x.z + x.w;
#pragma unroll
    for (int m = 32; m >= 1; m >>= 1) s += __shfl_xor(s, m);
    const float mu = s * (1.f / HID);
    float4 dx = {x.x - mu, x.y - mu, x.z - mu, x.w - mu};
    float sq = dx.x * dx.x + dx.y * dx.y + dx.z * dx.z + dx.w * dx.w;
#pragma unroll
    for (int m = 32; m >= 1; m >>= 1) sq += __shfl_xor(sq, m);
    const float r = rsqrtf(sq * (1.f / HID) + LN_EPS);
    float4 o;
    o.x = dx.x * r * g.x + bl.x;
    o.y = dx.y * r * g.y + bl.y;
    o.z = dx.z * r * g.z + bl.z;
    o.w = dx.w * r * g.w + bl.w;
    reinterpret_cast<float4*>(out + (row + 1) * HID)[lane] = o;
}

extern "C" void kernel_launch(void* const* d_in, const int* in_sizes, int n_in,
                              void* d_out, int out_size, void* d_ws, size_t ws_size,
                              hipStream_t stream) {
    const float* msg    = (const float*)d_in[0];
    const float* Wq     = (const float*)d_in[1];
    const float* Wk     = (const float*)d_in[2];
    const float* Wv     = (const float*)d_in[3];
    const float* Wr     = (const float*)d_in[4];
    const float* walpha = (const float*)d_in[5];
    const float* wbeta  = (const float*)d_in[6];
    const float* Wo     = (const float*)d_in[7];
    const float* bo     = (const float*)d_in[8];
    const float* gamma  = (const float*)d_in[9];
    const float* betaln = (const float*)d_in[10];
    const int*   seg    = (const int*)d_in[11];

    // workspace: msgb | qb | kb | vb | gq | gk ; act reuses msgb (msg dead after QKV),
    // tmp (bf16) reuses qb (dead after act). W casts fused into GEMM staging.
    char* ws = (char*)d_ws;
    const size_t nh = (size_t)N_BONDS * HID;
    size_t off = 0;
    bf16* msgb = (bf16*)(ws + off); off += nh * 2;
    bf16* qb   = (bf16*)(ws + off); off += nh * 2;
    bf16* kb   = (bf16*)(ws + off); off += nh * 2;
    bf16* vb   = (bf16*)(ws + off); off += nh * 2;
    float* gq  = (float*)(ws + off); off += (size_t)NSEG * HID * 4;
    float* gk  = (float*)(ws + off); off += (size_t)NSEG * HID * 4;
    bf16*  act = msgb;
    bf16*  tmp = qb;

    hipMemsetAsync(gq, 0, (size_t)2 * NSEG * HID * 4, stream);
    hipMemsetAsync(d_out, 0, HID * sizeof(float), stream);

    cast_kernel<<<4096, 256, 0, stream>>>(msg, (ushort*)msgb, (int)(nh / 4));

    dim3 gqkv(N_BONDS / 128, 6);
    qkv_gemm<<<gqkv, 256, 0, stream>>>((const ushort*)msgb, Wq, Wk, Wv, qb, kb, vb);

    alpha_gq_kernel<<<N_BONDS / CHUNK, 256, 0, stream>>>(qb, walpha, seg, gq);
    beta_gk_kernel<<<N_BONDS / CHUNK, 256, 0, stream>>>(kb, gq, wbeta, seg, gk);

    act_mfma_kernel<<<N_BONDS * 8 / 256, 256, 0, stream>>>((const ushort*)vb, (const ushort*)qb,
                                                           gk, Wr, seg, (ushort*)act);

    dim3 gg(N_BONDS / 128, 2);
    gemm_bt<ushort, bf16><<<gg, 256, 0, stream>>>((const ushort*)act, Wo, tmp);
    ln_kernel<<<N_BONDS / 4, 256, 0, stream>>>((const ushort*)tmp, bo, gamma, betaln, (float*)d_out);
}

// Round 23
// 586.472 us; speedup vs baseline: 1.2500x; 1.0062x over previous
//
#include <hip/hip_runtime.h>
#include <hip/hip_bf16.h>
#include <type_traits>

// ---- problem constants (fixed by the reference) ----
#define N_BONDS 196608
#define HID     256
#define NSEG    4096
#define SMSCALE 0.17677669529663687f  // D^-0.5, D=32
#define LN_EPS  1e-5f
#define CHUNK   8                     // bonds per block in segment kernels

typedef __hip_bfloat16 bf16;
typedef __attribute__((ext_vector_type(8))) short short8_t;  // 8 x bf16 (4 VGPR)
typedef __attribute__((ext_vector_type(4))) float f32x4_t;

__device__ __forceinline__ float bf2f(bf16 x) { return __bfloat162float(x); }
__device__ __forceinline__ short f2bs(float f) {
    union { bf16 b; short s; } cv; cv.b = __float2bfloat16(f); return cv.s;
}
__device__ __forceinline__ float us2f(ushort u) {
    union { ushort u; bf16 b; } cv; cv.u = u; return __bfloat162float(cv.b);
}

// 32-lane-group sum inside a 64-lane wave (xor masks < 32 stay inside the head group)
__device__ __forceinline__ float gsum32(float x) {
#pragma unroll
    for (int m = 16; m >= 1; m >>= 1) x += __shfl_xor(x, m);
    return x;
}

// ---------------- f32 -> bf16 cast (x4 vectorized) ----------------
__global__ void cast_kernel(const float* __restrict__ src, ushort* __restrict__ dst, int n4) {
    int i = blockIdx.x * blockDim.x + threadIdx.x;
    const int stride = gridDim.x * blockDim.x;
    for (; i < n4; i += stride) {
        float4 v = reinterpret_cast<const float4*>(src)[i];
        union { ushort4 u; bf16 b[4]; } cv;
        cv.b[0] = __float2bfloat16(v.x);
        cv.b[1] = __float2bfloat16(v.y);
        cv.b[2] = __float2bfloat16(v.z);
        cv.b[3] = __float2bfloat16(v.w);
        reinterpret_cast<ushort4*>(dst)[i] = cv.u;
    }
}

// ---------------- GEMM: C[n,j] = sum_i A[n,i] * W[j,i]  (torch Linear, B^T form) ----------------
// VERBATIM from R13/R17 (known-pass). W f32 -> bf16 during LDS staging; A bf16. Used for W_o.
template <typename AT, typename OutT>
__global__ __launch_bounds__(256, 2) void gemm_bt(const AT* __restrict__ A,
                                                  const float* __restrict__ W,
                                                  OutT* __restrict__ C) {
    __shared__ __align__(16) char lds[128 * 512];
    const int t = threadIdx.x;
    const int colhalf = blockIdx.y;
#pragma unroll
    for (int it = 0; it < 16; ++it) {
        int c = it * 256 + t;
        int j = c >> 5, kc = c & 31;
        const float* wp = W + ((colhalf << 7) + j) * HID + (kc << 3);
        float4 w0 = *reinterpret_cast<const float4*>(wp);
        float4 w1 = *reinterpret_cast<const float4*>(wp + 4);
        union { uint4 u; short s[8]; } cv;
        cv.s[0] = f2bs(w0.x); cv.s[1] = f2bs(w0.y); cv.s[2] = f2bs(w0.z); cv.s[3] = f2bs(w0.w);
        cv.s[4] = f2bs(w1.x); cv.s[5] = f2bs(w1.y); cv.s[6] = f2bs(w1.z); cv.s[7] = f2bs(w1.w);
        *reinterpret_cast<uint4*>(lds + j * 512 + ((kc << 4) ^ ((j & 7) << 4))) = cv.u;
    }
    __syncthreads();

    const int wave = t >> 6, lane = t & 63;
    const int lr = lane & 15, lk = lane >> 4;
    const long rowbase = (long)blockIdx.x * 128 + wave * 32;

    f32x4_t acc[2][8];
#pragma unroll
    for (int r = 0; r < 2; ++r)
#pragma unroll
        for (int cc = 0; cc < 8; ++cc) acc[r][cc] = (f32x4_t){0.f, 0.f, 0.f, 0.f};

    const AT* a0 = A + (rowbase + lr) * HID;
    const AT* a1 = a0 + 16 * HID;
#pragma unroll
    for (int k0 = 0; k0 < HID; k0 += 32) {
        const int koff = k0 + lk * 8;
        short8_t af0, af1;
        if constexpr (std::is_same_v<AT, float>) {
            float4 x0 = *reinterpret_cast<const float4*>(a0 + koff);
            float4 x1 = *reinterpret_cast<const float4*>(a0 + koff + 4);
            float4 y0 = *reinterpret_cast<const float4*>(a1 + koff);
            float4 y1 = *reinterpret_cast<const float4*>(a1 + koff + 4);
            af0[0] = f2bs(x0.x); af0[1] = f2bs(x0.y); af0[2] = f2bs(x0.z); af0[3] = f2bs(x0.w);
            af0[4] = f2bs(x1.x); af0[5] = f2bs(x1.y); af0[6] = f2bs(x1.z); af0[7] = f2bs(x1.w);
            af1[0] = f2bs(y0.x); af1[1] = f2bs(y0.y); af1[2] = f2bs(y0.z); af1[3] = f2bs(y0.w);
            af1[4] = f2bs(y1.x); af1[5] = f2bs(y1.y); af1[6] = f2bs(y1.z); af1[7] = f2bs(y1.w);
        } else {
            af0 = *reinterpret_cast<const short8_t*>(a0 + koff);
            af1 = *reinterpret_cast<const short8_t*>(a1 + koff);
        }
#pragma unroll
        for (int cc = 0; cc < 8; ++cc) {
            const int j = cc * 16 + lr;
            short8_t bfr = *reinterpret_cast<const short8_t*>(
                lds + j * 512 + (((k0 << 1) + (lk << 4)) ^ ((j & 7) << 4)));
            acc[0][cc] = __builtin_amdgcn_mfma_f32_16x16x32_bf16(af0, bfr, acc[0][cc], 0, 0, 0);
            acc[1][cc] = __builtin_amdgcn_mfma_f32_16x16x32_bf16(af1, bfr, acc[1][cc], 0, 0, 0);
        }
    }
    // C/D layout (verified m89): col = lane&15, row = (lane>>4)*4 + reg
#pragma unroll
    for (int r = 0; r < 2; ++r) {
#pragma unroll
        for (int cc = 0; cc < 8; ++cc) {
            const int col = (colhalf << 7) + cc * 16 + lr;
#pragma unroll
            for (int reg = 0; reg < 4; ++reg) {
                const long row = rowbase + r * 16 + lk * 4 + reg;
                const float v = acc[r][cc][reg];
                if constexpr (sizeof(OutT) == 2) C[row * HID + col] = __float2bfloat16(v);
                else                             C[row * HID + col] = v;
            }
        }
    }
}

// ---------------- merged QKV: 512 threads / 256 rows per block, 64KB W-half stage ------------
// R17 body (best-verified) with ONE parameter change: 8 waves per block instead of 4.
// LDS still allows 2 blocks/CU, but that is now 1024 threads/CU = 4 waves/SIMD (was 2) --
// double the latency hiding at identical traffic and per-wave work. grid = (N/256, 6).
__global__ __launch_bounds__(512, 4) void qkv_gemm(const ushort* __restrict__ A,
                                                   const float* __restrict__ Wq,
                                                   const float* __restrict__ Wk,
                                                   const float* __restrict__ Wv,
                                                   bf16* __restrict__ Q,
                                                   bf16* __restrict__ K,
                                                   bf16* __restrict__ V) {
    __shared__ __align__(16) char lds[128 * 512];
    const int t = threadIdx.x;
    const int which = blockIdx.y >> 1;
    const int colhalf = blockIdx.y & 1;
    const float* W = (which == 0) ? Wq : (which == 1) ? Wk : Wv;
    bf16* C = (which == 0) ? Q : (which == 1) ? K : V;

    // stage W half: 128 rows x 32 chunks of 8 f32 -> bf16; 4096 chunks / 512 threads = 8 it
#pragma unroll
    for (int it = 0; it < 8; ++it) {
        int c = it * 512 + t;
        int j = c >> 5, kc = c & 31;
        const float* wp = W + ((colhalf << 7) + j) * HID + (kc << 3);
        float4 w0 = *reinterpret_cast<const float4*>(wp);
        float4 w1 = *reinterpret_cast<const float4*>(wp + 4);
        union { uint4 u; short s[8]; } cv;
        cv.s[0] = f2bs(w0.x); cv.s[1] = f2bs(w0.y); cv.s[2] = f2bs(w0.z); cv.s[3] = f2bs(w0.w);
        cv.s[4] = f2bs(w1.x); cv.s[5] = f2bs(w1.y); cv.s[6] = f2bs(w1.z); cv.s[7] = f2bs(w1.w);
        *reinterpret_cast<uint4*>(lds + j * 512 + ((kc << 4) ^ ((j & 7) << 4))) = cv.u;
    }
    __syncthreads();

    const int wave = t >> 6, lane = t & 63;          // wave 0..7
    const int lr = lane & 15, lk = lane >> 4;
    const long rowbase = (long)blockIdx.x * 256 + wave * 32;

    f32x4_t acc[2][8];
#pragma unroll
    for (int r = 0; r < 2; ++r)
#pragma unroll
        for (int cc = 0; cc < 8; ++cc) acc[r][cc] = (f32x4_t){0.f, 0.f, 0.f, 0.f};

    const ushort* a0 = A + (rowbase + lr) * HID;
    const ushort* a1 = a0 + 16 * HID;
#pragma unroll
    for (int k0 = 0; k0 < HID; k0 += 32) {
        const int koff = k0 + lk * 8;
        short8_t af0 = *reinterpret_cast<const short8_t*>(a0 + koff);
        short8_t af1 = *reinterpret_cast<const short8_t*>(a1 + koff);
#pragma unroll
        for (int cc = 0; cc < 8; ++cc) {
            const int j = cc * 16 + lr;
            short8_t bfr = *reinterpret_cast<const short8_t*>(
                lds + j * 512 + (((k0 << 1) + (lk << 4)) ^ ((j & 7) << 4)));
            acc[0][cc] = __builtin_amdgcn_mfma_f32_16x16x32_bf16(af0, bfr, acc[0][cc], 0, 0, 0);
            acc[1][cc] = __builtin_amdgcn_mfma_f32_16x16x32_bf16(af1, bfr, acc[1][cc], 0, 0, 0);
        }
    }
#pragma unroll
    for (int r = 0; r < 2; ++r) {
#pragma unroll
        for (int cc = 0; cc < 8; ++cc) {
            const int col = (colhalf << 7) + cc * 16 + lr;
#pragma unroll
            for (int reg = 0; reg < 4; ++reg) {
                const long row = rowbase + r * 16 + lk * 4 + reg;
                C[row * HID + col] = __float2bfloat16(acc[r][cc][reg]);
            }
        }
    }
}

// ---------------- alpha = softmax_d(q*w_alpha*scale); gq = segment_sum(alpha*q) ----------------
// VERBATIM from R10 (known-pass).
__global__ __launch_bounds__(256) void alpha_gq_kernel(const bf16* __restrict__ qb,
                                                       const float* __restrict__ w_alpha,
                                                       const int* __restrict__ seg,
                                                       float* __restrict__ gq) {
    const int j = threadIdx.x;
    const float wa = w_alpha[j & 31] * SMSCALE;
    const long n0 = (long)blockIdx.x * CHUNK;
    float acc = 0.f;
    int cur = -1;
    for (int i = 0; i < CHUNK; ++i) {
        const long n = n0 + i;
        const int s = seg[n];
        const float qv = bf2f(qb[n * HID + j]);
        const float e = __expf(qv * wa);
        const float ssum = gsum32(e);
        const float alpha = e / ssum;
        if (s != cur) {
            if (cur >= 0) atomicAdd(&gq[(long)cur * HID + j], acc);
            acc = 0.f;
            cur = s;
        }
        acc += alpha * qv;
    }
    atomicAdd(&gq[(long)cur * HID + j], acc);
}

// ---------------- p = gq[seg]*k; beta = softmax_d(p*w_beta*scale); gk = segment_sum(beta*p) ----
// VERBATIM from R10 (known-pass).
__global__ __launch_bounds__(256) void beta_gk_kernel(const bf16* __restrict__ kb,
                                                      const float* __restrict__ gq,
                                                      const float* __restrict__ w_beta,
                                                      const int* __restrict__ seg,
                                                      float* __restrict__ gk) {
    const int j = threadIdx.x;
    const float wb = w_beta[j & 31] * SMSCALE;
    const long n0 = (long)blockIdx.x * CHUNK;
    float acc = 0.f;
    int cur = -1;
    for (int i = 0; i < CHUNK; ++i) {
        const long n = n0 + i;
        const int s = seg[n];
        const float kv = bf2f(kb[n * HID + j]);
        const float p = gq[(long)s * HID + j] * kv;
        const float e = __expf(p * wb);
        const float ssum = gsum32(e);
        const float beta = e / ssum;
        if (s != cur) {
            if (cur >= 0) atomicAdd(&gk[(long)cur * HID + j], acc);
            acc = 0.f;
            cur = s;
        }
        acc += beta * p;
    }
    atomicAdd(&gk[(long)cur * HID + j], acc);
}

// ---------------- act = relu((gk[seg]*v) @ W_r^T per head + q) via bf16 hi/lo MFMA -----------
// VERBATIM from R12/R13/R17 (known-pass).
__global__ __launch_bounds__(256) void act_mfma_kernel(const ushort* __restrict__ vb,
                                                       const ushort* __restrict__ qb,
                                                       const float* __restrict__ gk,
                                                       const float* __restrict__ Wr,
                                                       const int* __restrict__ seg,
                                                       ushort* __restrict__ act) {
    const int t = threadIdx.x;
    const int wave = t >> 6, lane = t & 63;
    const int lr = lane & 15, lk = lane >> 4;

    short8_t bhi[2], blo[2];
#pragma unroll
    for (int ct = 0; ct < 2; ++ct) {
        const float* wr = Wr + (ct * 16 + lr) * 32 + lk * 8;
#pragma unroll
        for (int e = 0; e < 8; ++e) {
            const float w = wr[e];
            const short h = f2bs(w);
            bhi[ct][e] = h;
            blo[ct][e] = f2bs(w - us2f((ushort)h));
        }
    }

    const long rowblock = (long)blockIdx.x * 256 + wave * 64;
#pragma unroll
    for (int rt = 0; rt < 4; ++rt) {
        const long rtbase = rowblock + rt * 16;
        const long arow = rtbase + lr;
        const int n = (int)(arow >> 3), h = (int)(arow & 7);
        const int sid = seg[n];
        short8_t v8 = *reinterpret_cast<const short8_t*>(vb + arow * 32 + lk * 8);
        const float* gp = gk + (long)sid * HID + h * 32 + lk * 8;
        float4 g0 = *reinterpret_cast<const float4*>(gp);
        float4 g1 = *reinterpret_cast<const float4*>(gp + 4);
        float kvi[8];
        kvi[0] = g0.x * us2f((ushort)v8[0]);
        kvi[1] = g0.y * us2f((ushort)v8[1]);
        kvi[2] = g0.z * us2f((ushort)v8[2]);
        kvi[3] = g0.w * us2f((ushort)v8[3]);
        kvi[4] = g1.x * us2f((ushort)v8[4]);
        kvi[5] = g1.y * us2f((ushort)v8[5]);
        kvi[6] = g1.z * us2f((ushort)v8[6]);
        kvi[7] = g1.w * us2f((ushort)v8[7]);
        short8_t ahi, alo;
#pragma unroll
        for (int e = 0; e < 8; ++e) {
            const short hh = f2bs(kvi[e]);
            ahi[e] = hh;
            alo[e] = f2bs(kvi[e] - us2f((ushort)hh));
        }
#pragma unroll
        for (int ct = 0; ct < 2; ++ct) {
            f32x4_t c = (f32x4_t){0.f, 0.f, 0.f, 0.f};
            c = __builtin_amdgcn_mfma_f32_16x16x32_bf16(ahi, bhi[ct], c, 0, 0, 0);
            c = __builtin_amdgcn_mfma_f32_16x16x32_bf16(alo, bhi[ct], c, 0, 0, 0);
            c = __builtin_amdgcn_mfma_f32_16x16x32_bf16(ahi, blo[ct], c, 0, 0, 0);
#pragma unroll
            for (int reg = 0; reg < 4; ++reg) {
                const long row = rtbase + lk * 4 + reg;
                const long idx = row * 32 + ct * 16 + lr;
                act[idx] = (ushort)f2bs(fmaxf(c[reg] + us2f(qb[idx]), 0.f));
            }
        }
    }
}

// ---------------- LayerNorm: one wave per row, bf16 tmp input, write d_out row n+1 ----------
// VERBATIM from R11/R13/R17 (known-pass).
__global__ __launch_bounds__(256) void ln_kernel(const ushort* __restrict__ tmp,
                                                 const float* __restrict__ b_o,
                                                 const float* __restrict__ gamma,
                                                 const float* __restrict__ beta_ln,
                                                 float* __restrict__ out) {
    const int wave = threadIdx.x >> 6, lane = threadIdx.x & 63;
    const long row = (long)blockIdx.x * 4 + wave;
    const float4 bo = reinterpret_cast<const float4*>(b_o)[lane];
    const float4 g = reinterpret_cast<const float4*>(gamma)[lane];
    const float4 bl = reinterpret_cast<const float4*>(beta_ln)[lane];
    const ushort4 xr = reinterpret_cast<const ushort4*>(tmp + row * HID)[lane];
    float4 x = {us2f(xr.x) + bo.x, us2f(xr.y) + bo.y, us2f(xr.z) + bo.z, us2f(xr.w) + bo.w};
    float s = x.x + x.y + x.z + x.w;
#pragma unroll
    for (int m = 32; m >= 1; m >>= 1) s += __shfl_xor(s, m);
    const float mu = s * (1.f / HID);
    float4 dx = {x.x - mu, x.y - mu, x.z - mu, x.w - mu};
    float sq = dx.x * dx.x + dx.y * dx.y + dx.z * dx.z + dx.w * dx.w;
#pragma unroll
    for (int m = 32; m >= 1; m >>= 1) sq += __shfl_xor(sq, m);
    const float r = rsqrtf(sq * (1.f / HID) + LN_EPS);
    float4 o;
    o.x = dx.x * r * g.x + bl.x;
    o.y = dx.y * r * g.y + bl.y;
    o.z = dx.z * r * g.z + bl.z;
    o.w = dx.w * r * g.w + bl.w;
    reinterpret_cast<float4*>(out + (row + 1) * HID)[lane] = o;
}

extern "C" void kernel_launch(void* const* d_in, const int* in_sizes, int n_in,
                              void* d_out, int out_size, void* d_ws, size_t ws_size,
                              hipStream_t stream) {
    const float* msg    = (const float*)d_in[0];
    const float* Wq     = (const float*)d_in[1];
    const float* Wk     = (const float*)d_in[2];
    const float* Wv     = (const float*)d_in[3];
    const float* Wr     = (const float*)d_in[4];
    const float* walpha = (const float*)d_in[5];
    const float* wbeta  = (const float*)d_in[6];
    const float* Wo     = (const float*)d_in[7];
    const float* bo     = (const float*)d_in[8];
    const float* gamma  = (const float*)d_in[9];
    const float* betaln = (const float*)d_in[10];
    const int*   seg    = (const int*)d_in[11];

    // workspace: msgb | qb | kb | vb | gq | gk ; act reuses msgb (msg dead after QKV),
    // tmp (bf16) reuses qb (dead after act). W casts fused into GEMM staging.
    char* ws = (char*)d_ws;
    const size_t nh = (size_t)N_BONDS * HID;
    size_t off = 0;
    bf16* msgb = (bf16*)(ws + off); off += nh * 2;
    bf16* qb   = (bf16*)(ws + off); off += nh * 2;
    bf16* kb   = (bf16*)(ws + off); off += nh * 2;
    bf16* vb   = (bf16*)(ws + off); off += nh * 2;
    float* gq  = (float*)(ws + off); off += (size_t)NSEG * HID * 4;
    float* gk  = (float*)(ws + off); off += (size_t)NSEG * HID * 4;
    bf16*  act = msgb;
    bf16*  tmp = qb;

    hipMemsetAsync(gq, 0, (size_t)2 * NSEG * HID * 4, stream);
    hipMemsetAsync(d_out, 0, HID * sizeof(float), stream);

    cast_kernel<<<4096, 256, 0, stream>>>(msg, (ushort*)msgb, (int)(nh / 4));

    dim3 gqkv(N_BONDS / 256, 6);
    qkv_gemm<<<gqkv, 512, 0, stream>>>((const ushort*)msgb, Wq, Wk, Wv, qb, kb, vb);

    alpha_gq_kernel<<<N_BONDS / CHUNK, 256, 0, stream>>>(qb, walpha, seg, gq);
    beta_gk_kernel<<<N_BONDS / CHUNK, 256, 0, stream>>>(kb, gq, wbeta, seg, gk);

    act_mfma_kernel<<<N_BONDS * 8 / 256, 256, 0, stream>>>((const ushort*)vb, (const ushort*)qb,
                                                           gk, Wr, seg, (ushort*)act);

    dim3 gg(N_BONDS / 128, 2);
    gemm_bt<ushort, bf16><<<gg, 256, 0, stream>>>((const ushort*)act, Wo, tmp);
    ln_kernel<<<N_BONDS / 4, 256, 0, stream>>>((const ushort*)tmp, bo, gamma, betaln, (float*)d_out);
}